// Round 1
// baseline (2664.428 us; speedup 1.0000x reference)
//
#include <hip/hip_runtime.h>
#include <hip/hip_bf16.h>

// ---------------------------------------------------------------------------
// Problem constants (from reference)
// ---------------------------------------------------------------------------
#define HDIM 512
#define KA   128
#define VOC  32000
#define ANUMC 20
#define NSEQ 64
#define BATCH 32
#define TLEN 256
#define SLEN 32
#define ALEN 5
#define NB   2048          // NSEQ*BATCH
#define CIN  1664          // 3H + KA
#define G3H  1536

typedef __bf16 bf16;
typedef bf16 v8bf __attribute__((ext_vector_type(8)));
typedef float v4f __attribute__((ext_vector_type(4)));

#define DEV __device__ __forceinline__

DEV float sigmoidf_(float x) { return 1.f / (1.f + expf(-x)); }

// ---------------------------------------------------------------------------
// k_zero: zero the barrier region (ws is poisoned 0xAA before every launch)
// ---------------------------------------------------------------------------
__global__ void k_zero(int* bar) { bar[threadIdx.x] = 0; }

// ---------------------------------------------------------------------------
// k_vec: small precomputations
//  u1a = attn_W[:, :H].T @ attn_v      (512)   @ misc+0
//  u1e = attn_W[:, H:].T @ attn_v      (512)   @ misc+512
//  u3h = attr_W[:, :H].T @ attr_v      (512)   @ misc+1024
//  u3e = attr_W[:, H:].T @ attr_v      (128)   @ misc+1536
//  bv1 = dot(attn_b, attn_v)                   @ misc+1664
//  bv3 = dot(attr_b, attr_v)                   @ misc+1665
//  e4[b,j] (proj of concat(enc4[0],enc4[1]))   @ misc+1792 (640)
// ---------------------------------------------------------------------------
__global__ void k_vec(const float* __restrict__ attn_W, const float* __restrict__ attn_b,
                      const float* __restrict__ attn_v,
                      const float* __restrict__ attr_W, const float* __restrict__ attr_b,
                      const float* __restrict__ attr_v,
                      const float* __restrict__ enc4, const float* __restrict__ pW,
                      const float* __restrict__ pb, float* __restrict__ misc) {
  int tid = threadIdx.x;
  int blk = blockIdx.x;
  if (blk == 0) {
    for (int i = tid; i < 512; i += 256) {
      float s = 0.f;
      for (int j = 0; j < 512; ++j) s += attn_W[j * 1024 + i] * attn_v[j];
      misc[i] = s;
    }
  } else if (blk == 1) {
    for (int i = tid; i < 512; i += 256) {
      float s = 0.f;
      for (int j = 0; j < 512; ++j) s += attn_W[j * 1024 + 512 + i] * attn_v[j];
      misc[512 + i] = s;
    }
  } else if (blk == 2) {
    for (int i = tid; i < 512; i += 256) {
      float s = 0.f;
      for (int j = 0; j < 512; ++j) s += attr_W[j * 640 + i] * attr_v[j];
      misc[1024 + i] = s;
    }
  } else {
    for (int i = tid; i < 128; i += 256) {
      float s = 0.f;
      for (int j = 0; j < 512; ++j) s += attr_W[j * 640 + 512 + i] * attr_v[j];
      misc[1536 + i] = s;
    }
    if (tid == 128) {
      float s = 0.f;
      for (int j = 0; j < 512; ++j) s += attn_b[j] * attn_v[j];
      misc[1664] = s;
    }
    if (tid == 129) {
      float s = 0.f;
      for (int j = 0; j < 512; ++j) s += attr_b[j] * attr_v[j];
      misc[1665] = s;
    }
    for (int i = tid; i < BATCH * ANUMC; i += 256) {
      int b = i / ANUMC, j = i % ANUMC;
      float s = pb[j];
      for (int q = 0; q < ANUMC; ++q) s += pW[j * 40 + q] * enc4[b * ANUMC + q];
      for (int q = 0; q < ANUMC; ++q) s += pW[j * 40 + 20 + q] * enc4[BATCH * ANUMC + b * ANUMC + q];
      misc[1792 + i] = s;
    }
  }
}

// ---------------------------------------------------------------------------
// k_embcvt: embedding gather (fp32 + bf16) and weight fp32->bf16 conversions
// segments: [0, 1048576)        embedded / emb_bf
//           [.., +786432)       Wih_bf
//           [.., +851968)       cW_bf
//           [.., +16384000)     oW_bf
//           [.., +1048576)      Whh_pad (128 blocks x 16 rows x 512, bf16)
// total 20,119,552 -> grid 78592 x 256
// ---------------------------------------------------------------------------
__global__ void k_embcvt(const int* __restrict__ seq, const float* __restrict__ emb,
                         float* __restrict__ embedded, bf16* __restrict__ emb_bf,
                         const float* __restrict__ Wih, bf16* __restrict__ Wih_bf,
                         const float* __restrict__ cW, bf16* __restrict__ cW_bf,
                         const float* __restrict__ oW, bf16* __restrict__ oW_bf,
                         const float* __restrict__ Whh, bf16* __restrict__ Whh_pad) {
  size_t i = (size_t)blockIdx.x * 256 + threadIdx.x;
  const size_t s0 = 1048576, s1 = s0 + 786432, s2 = s1 + 851968, s3 = s2 + 16384000;
  if (i < s0) {
    int row = (int)(i >> 9), col = (int)(i & 511);
    float v = emb[(size_t)seq[row] * 512 + col];
    embedded[i] = v;
    emb_bf[i] = (bf16)v;
  } else if (i < s1) {
    size_t j = i - s0;
    Wih_bf[j] = (bf16)Wih[j];
  } else if (i < s2) {
    size_t j = i - s1;
    cW_bf[j] = (bf16)cW[j];
  } else if (i < s3) {
    size_t j = i - s2;
    oW_bf[j] = (bf16)oW[j];
  } else {
    size_t j = i - s3;  // < 1048576
    int blk = (int)(j >> 13);          // 16*512 per block
    int rr = (int)((j >> 9) & 15);
    int kk = (int)(j & 511);
    float v = 0.f;
    if (rr < 12) {
      int g = rr >> 2, cl = rr & 3;
      v = Whh[(size_t)(g * 512 + blk * 4 + cl) * 512 + kk];
    }
    Whh_pad[j] = (bf16)v;
  }
}

// ---------------------------------------------------------------------------
// k_c: c1[t*32+b] = enc1[t,b,:] . u1e ; c2 (enc2, u1e) ; c3 (enc3, u3e)
// ---------------------------------------------------------------------------
__global__ void k_c(const float* __restrict__ enc1, const float* __restrict__ enc2,
                    const float* __restrict__ enc3, float* __restrict__ misc) {
  int i = blockIdx.x * 256 + threadIdx.x;
  const float* u1e = misc + 512;
  const float* u3e = misc + 1536;
  if (i < 8192) {
    const float* row = enc1 + (size_t)i * 512;
    float s = 0.f;
#pragma unroll 4
    for (int j = 0; j < 512; j += 4) {
      float4 a = *(const float4*)(row + j);
      float4 u = *(const float4*)(u1e + j);
      s += a.x * u.x + a.y * u.y + a.z * u.z + a.w * u.w;
    }
    misc[2560 + i] = s;
  } else if (i < 8192 + 1024) {
    int k = i - 8192;
    const float* row = enc2 + (size_t)k * 512;
    float s = 0.f;
#pragma unroll 4
    for (int j = 0; j < 512; j += 4) {
      float4 a = *(const float4*)(row + j);
      float4 u = *(const float4*)(u1e + j);
      s += a.x * u.x + a.y * u.y + a.z * u.z + a.w * u.w;
    }
    misc[10752 + k] = s;
  } else if (i < 8192 + 1024 + 160) {
    int k = i - 9216;
    const float* row = enc3 + (size_t)k * 128;
    float s = 0.f;
#pragma unroll 4
    for (int j = 0; j < 128; j += 4) {
      float4 a = *(const float4*)(row + j);
      float4 u = *(const float4*)(u3e + j);
      s += a.x * u.x + a.y * u.y + a.z * u.z + a.w * u.w;
    }
    misc[11776 + k] = s;
  }
}

// ---------------------------------------------------------------------------
// Generic NT GEMM: C[m,n] = sum_k A[m,k]*B[n,k] (+bias[n])
// 128x128 tile, BK=64, 4 waves, mfma_f32_16x16x32_bf16, XOR-swizzled LDS.
// EPI 0: Cf = acc+bias (fp32) ; EPI 1: Cb = bf16(tanh(acc+bias))
// Requires M%128==0, N%128==0, K%64==0.
// ---------------------------------------------------------------------------
template <int EPI>
__global__ __launch_bounds__(256) void k_gemm_bt(const bf16* __restrict__ A,
                                                 const bf16* __restrict__ Bm,
                                                 const float* __restrict__ bias,
                                                 float* __restrict__ Cf, bf16* __restrict__ Cb,
                                                 int M, int Nn, int Kd) {
  __shared__ __align__(16) unsigned short As[128 * 64];
  __shared__ __align__(16) unsigned short Bs[128 * 64];
  int tid = threadIdx.x;
  int m0 = blockIdx.y * 128;
  int n0 = blockIdx.x * 128;
  int lane = tid & 63;
  int wv = tid >> 6;
  int wm = wv & 1, wn = wv >> 1;
  int l15 = lane & 15, quad = lane >> 4;
  int srow = tid >> 3;  // 0..31
  int sch = tid & 7;    // 0..7

  v4f acc[4][4];
#pragma unroll
  for (int i = 0; i < 4; ++i)
#pragma unroll
    for (int j = 0; j < 4; ++j) acc[i][j] = (v4f){0.f, 0.f, 0.f, 0.f};

  for (int kb = 0; kb < Kd; kb += 64) {
#pragma unroll
    for (int r = 0; r < 4; ++r) {
      int row = r * 32 + srow;
      uint4 va = *(const uint4*)(A + (size_t)(m0 + row) * Kd + kb + sch * 8);
      *(uint4*)((char*)As + row * 128 + ((sch ^ (row & 7)) << 4)) = va;
      uint4 vb = *(const uint4*)(Bm + (size_t)(n0 + row) * Kd + kb + sch * 8);
      *(uint4*)((char*)Bs + row * 128 + ((sch ^ (row & 7)) << 4)) = vb;
    }
    __syncthreads();
#pragma unroll
    for (int ks = 0; ks < 2; ++ks) {
      v8bf af[4], bfr[4];
      int c = ks * 4 + quad;
#pragma unroll
      for (int i = 0; i < 4; ++i) {
        int mr = wm * 64 + i * 16 + l15;
        af[i] = *(const v8bf*)((const char*)As + mr * 128 + ((c ^ (mr & 7)) << 4));
      }
#pragma unroll
      for (int j = 0; j < 4; ++j) {
        int nr = wn * 64 + j * 16 + l15;
        bfr[j] = *(const v8bf*)((const char*)Bs + nr * 128 + ((c ^ (nr & 7)) << 4));
      }
#pragma unroll
      for (int i = 0; i < 4; ++i)
#pragma unroll
        for (int j = 0; j < 4; ++j)
          acc[i][j] = __builtin_amdgcn_mfma_f32_16x16x32_bf16(af[i], bfr[j], acc[i][j], 0, 0, 0);
    }
    __syncthreads();
  }
  // epilogue: C/D layout col = lane&15, row = quad*4 + reg  [m89/m91]
#pragma unroll
  for (int i = 0; i < 4; ++i) {
    int gr0 = m0 + wm * 64 + i * 16 + quad * 4;
#pragma unroll
    for (int j = 0; j < 4; ++j) {
      int gc = n0 + wn * 64 + j * 16 + l15;
      float bs = bias[gc];
#pragma unroll
      for (int reg = 0; reg < 4; ++reg) {
        float v = acc[i][j][reg] + bs;
        if (EPI == 1)
          Cb[(size_t)(gr0 + reg) * Nn + gc] = (bf16)tanhf(v);
        else
          Cf[(size_t)(gr0 + reg) * Nn + gc] = v;
      }
    }
  }
}

// ---------------------------------------------------------------------------
// k_gru: persistent recurrence. 128 blocks x 256 threads; block owns 4 h-cols.
// Per step: stage h(bf16) to LDS; waves 0-1 do MFMA 32x16x512 against the
// block's LDS-resident 16 padded Whh rows; combine gates; grid barrier.
// ---------------------------------------------------------------------------
__global__ __launch_bounds__(256) void k_gru(const float* __restrict__ gi,
                                             const bf16* __restrict__ Whh_pad,
                                             const float* __restrict__ bhh,
                                             const float* __restrict__ lasth,
                                             float* __restrict__ rnn,
                                             bf16* __restrict__ concat_bf,
                                             int* __restrict__ bar) {
  __shared__ __align__(16) unsigned short hs[32 * 512];     // 32 KB
  __shared__ __align__(16) unsigned short whh_s[16 * 512];  // 16 KB
  __shared__ float gh_s[32 * 16];
  __shared__ float hprev_s[128];
  int tid = threadIdx.x;
  int blk = blockIdx.x;

  // load the block's 16 padded Whh rows once (XOR-swizzled chunks)
  for (int rnd = 0; rnd < 4; ++rnd) {
    int ch = rnd * 256 + tid;  // 0..1023
    int row = ch >> 6, cc = ch & 63;
    uint4 v = *(const uint4*)(Whh_pad + (size_t)(blk * 16 + row) * 512 + cc * 8);
    *(uint4*)((char*)whh_s + row * 1024 + ((cc ^ (row & 7)) << 4)) = v;
  }
  int cb = tid >> 2;   // batch for combine phase (tid<128)
  int cl = tid & 3;
  int c = blk * 4 + cl;
  if (tid < 128) hprev_s[tid] = lasth[cb * 512 + c];

  int w = tid >> 6;           // wave id
  int lane = tid & 63;
  int l15 = lane & 15, quad = lane >> 4;
  int m = w * 16 + l15;       // batch row for MFMA (waves 0,1)
  float b_r = bhh[c], b_z = bhh[512 + c], b_n = bhh[1024 + c];

  for (int t = 0; t < 64; ++t) {
    // ---- stage h (bf16) into LDS ----
    for (int rnd = 0; rnd < 8; ++rnd) {
      int ch = rnd * 256 + tid;  // 0..2047
      int bb = ch >> 6, cc = ch & 63;
      char* dst = (char*)hs + bb * 1024 + ((cc ^ (bb & 7)) << 4);
      if (t == 0) {
        const float* hp = lasth + bb * 512 + cc * 8;
        float4 x = *(const float4*)hp;
        float4 y = *(const float4*)(hp + 4);
        v8bf vv;
        vv[0] = (bf16)x.x; vv[1] = (bf16)x.y; vv[2] = (bf16)x.z; vv[3] = (bf16)x.w;
        vv[4] = (bf16)y.x; vv[5] = (bf16)y.y; vv[6] = (bf16)y.z; vv[7] = (bf16)y.w;
        *(v8bf*)dst = vv;
      } else {
        uint4 v = *(const uint4*)(concat_bf + ((size_t)(t - 1) * 32 + bb) * CIN + cc * 8);
        *(uint4*)dst = v;
      }
    }
    __syncthreads();
    // ---- MFMA: gh[b, n] for 16 padded gate rows (waves 0-1) ----
    if (tid < 128) {
      v4f acc = (v4f){0.f, 0.f, 0.f, 0.f};
#pragma unroll
      for (int it = 0; it < 16; ++it) {
        int cc = it * 4 + quad;
        v8bf af = *(const v8bf*)((const char*)hs + m * 1024 + ((cc ^ (m & 7)) << 4));
        v8bf bfr = *(const v8bf*)((const char*)whh_s + l15 * 1024 + ((cc ^ (l15 & 7)) << 4));
        acc = __builtin_amdgcn_mfma_f32_16x16x32_bf16(af, bfr, acc, 0, 0, 0);
      }
#pragma unroll
      for (int reg = 0; reg < 4; ++reg)
        gh_s[(w * 16 + quad * 4 + reg) * 16 + l15] = acc[reg];
    }
    __syncthreads();
    // ---- combine gates, write h_new ----
    if (tid < 128) {
      float ar = gh_s[cb * 16 + cl] + b_r;
      float az = gh_s[cb * 16 + 4 + cl] + b_z;
      float an = gh_s[cb * 16 + 8 + cl] + b_n;
      const float* gii = gi + ((size_t)t * 32 + cb) * G3H;
      float rg = sigmoidf_(gii[c] + ar);
      float zg = sigmoidf_(gii[512 + c] + az);
      float ng = tanhf(gii[1024 + c] + rg * an);
      float hp = hprev_s[tid];
      float hn = (1.f - zg) * ng + zg * hp;
      rnn[((size_t)t * 32 + cb) * 512 + c] = hn;
      concat_bf[((size_t)t * 32 + cb) * CIN + c] = (bf16)hn;
      hprev_s[tid] = hn;
    }
    __threadfence();
    __syncthreads();
    if (t < 63) {
      if (tid == 0) {
        __hip_atomic_fetch_add(bar, 1, __ATOMIC_RELAXED, __HIP_MEMORY_SCOPE_AGENT);
        int target = 128 * (t + 1);
        while (__hip_atomic_load(bar, __ATOMIC_RELAXED, __HIP_MEMORY_SCOPE_AGENT) < target)
          __builtin_amdgcn_s_sleep(2);
      }
      __syncthreads();
      __threadfence();
    }
  }
}

// ---------------------------------------------------------------------------
// k_attnrow: per (n,b) row: a1,a3 dots + all three softmaxes -> aw1,aw2,aw3
// one wave per row; 4 waves per block; grid 512.
// ---------------------------------------------------------------------------
__global__ __launch_bounds__(256) void k_attnrow(const float* __restrict__ rnn,
                                                 const float* __restrict__ misc,
                                                 float* __restrict__ aw1,
                                                 float* __restrict__ aw2,
                                                 float* __restrict__ aw3) {
  int wv = (blockIdx.x * 256 + threadIdx.x) >> 6;
  int lane = threadIdx.x & 63;
  if (wv >= 2048) return;
  int n = wv >> 5, b = wv & 31;
  const float* u1a = misc;
  const float* u3h = misc + 1024;
  const float* c1 = misc + 2560;
  const float* c2 = misc + 10752;
  const float* c3 = misc + 11776;
  const float* row = rnn + (size_t)(n * 32 + b) * 512;
  float s1 = 0.f, s3 = 0.f;
#pragma unroll
  for (int q = 0; q < 8; ++q) {
    int j = lane * 8 + q;
    float rv = row[j];
    s1 += rv * u1a[j];
    s3 += rv * u3h[j];
  }
  for (int o = 32; o > 0; o >>= 1) {
    s1 += __shfl_down(s1, o);
    s3 += __shfl_down(s3, o);
  }
  s1 = __shfl(s1, 0) + misc[1664];
  s3 = __shfl(s3, 0) + misc[1665];

  // aw1 over T=256
  float e[4];
  float mx = -1e30f;
#pragma unroll
  for (int q = 0; q < 4; ++q) {
    int t = q * 64 + lane;
    e[q] = tanhf(s1 + c1[t * 32 + b]);
    mx = fmaxf(mx, e[q]);
  }
  for (int o = 32; o > 0; o >>= 1) mx = fmaxf(mx, __shfl_xor(mx, o));
  float sum = 0.f;
#pragma unroll
  for (int q = 0; q < 4; ++q) {
    e[q] = expf(e[q] - mx);
    sum += e[q];
  }
  for (int o = 32; o > 0; o >>= 1) sum += __shfl_xor(sum, o);
  float inv = 1.f / sum;
  size_t base1 = (size_t)(b * 64 + n) * 256;
#pragma unroll
  for (int q = 0; q < 4; ++q) aw1[base1 + q * 64 + lane] = e[q] * inv;

  // aw2 over S=32
  float e2 = (lane < 32) ? tanhf(s1 + c2[lane * 32 + b]) : -1e30f;
  float m2 = e2;
  for (int o = 32; o > 0; o >>= 1) m2 = fmaxf(m2, __shfl_xor(m2, o));
  float x2 = (lane < 32) ? expf(e2 - m2) : 0.f;
  float sm2 = x2;
  for (int o = 32; o > 0; o >>= 1) sm2 += __shfl_xor(sm2, o);
  if (lane < 32) aw2[(size_t)(b * 64 + n) * 32 + lane] = x2 / sm2;

  // aw3 over A=5
  float e3 = (lane < 5) ? tanhf(s3 + c3[lane * 32 + b]) : -1e30f;
  float m3 = e3;
  for (int o = 32; o > 0; o >>= 1) m3 = fmaxf(m3, __shfl_xor(m3, o));
  float x3 = (lane < 5) ? expf(e3 - m3) : 0.f;
  float sm3 = x3;
  for (int o = 32; o > 0; o >>= 1) sm3 += __shfl_xor(sm3, o);
  if (lane < 5) aw3[(size_t)(b * 64 + n) * 5 + lane] = x3 / sm3;
}

// ---------------------------------------------------------------------------
// k_ctx: ctx[n,b,col] = sum_te aw[b,n,te]*enc[te,b,col] -> bf16 into concat.
// grid 128: b(32) x q(2: 256-col half) x nh(2: 32-n half).
// awsT staged transposed [te][36-padded n] so inner loop reads float4 over n.
// ---------------------------------------------------------------------------
template <int TL, int COFF>
__global__ __launch_bounds__(256) void k_ctx(const float* __restrict__ aw,
                                             const float* __restrict__ enc,
                                             bf16* __restrict__ concat_bf) {
  __shared__ __align__(16) float awsT[TL * 36];
  int tid = threadIdx.x;
  int bx = blockIdx.x;
  int b = bx >> 2, q = (bx >> 1) & 1, nh = bx & 1;
  for (int i = tid; i < 32 * TL; i += 256) {
    int n = i / TL, te = i % TL;
    awsT[te * 36 + n] = aw[(size_t)b * 64 * TL + (size_t)(nh * 32 + n) * TL + te];
  }
  __syncthreads();
  int col = q * 256 + tid;
  float4 acc[8];
#pragma unroll
  for (int n4 = 0; n4 < 8; ++n4) acc[n4] = make_float4(0.f, 0.f, 0.f, 0.f);
  for (int te = 0; te < TL; ++te) {
    float v = enc[((size_t)te * 32 + b) * 512 + col];
#pragma unroll
    for (int n4 = 0; n4 < 8; ++n4) {
      float4 wv = *(const float4*)(awsT + te * 36 + n4 * 4);
      acc[n4].x += wv.x * v;
      acc[n4].y += wv.y * v;
      acc[n4].z += wv.z * v;
      acc[n4].w += wv.w * v;
    }
  }
#pragma unroll
  for (int n4 = 0; n4 < 8; ++n4) {
    int ng = nh * 32 + n4 * 4;
    concat_bf[((size_t)(ng + 0) * 32 + b) * CIN + COFF + col] = (bf16)acc[n4].x;
    concat_bf[((size_t)(ng + 1) * 32 + b) * CIN + COFF + col] = (bf16)acc[n4].y;
    concat_bf[((size_t)(ng + 2) * 32 + b) * CIN + COFF + col] = (bf16)acc[n4].z;
    concat_bf[((size_t)(ng + 3) * 32 + b) * CIN + COFF + col] = (bf16)acc[n4].w;
  }
}

// ---------------------------------------------------------------------------
// k_ctx3_misc: ctx3 (5-term) into concat cols [1536,1664) + hidden copy
// ---------------------------------------------------------------------------
__global__ void k_ctx3_misc(const float* __restrict__ aw3, const float* __restrict__ enc3,
                            const float* __restrict__ rnn, bf16* __restrict__ concat_bf,
                            float* __restrict__ hid) {
  int i = blockIdx.x * 256 + threadIdx.x;
  if (i < NB * 128) {
    int row = i >> 7, k = i & 127;
    int n = row >> 5, b = row & 31;
    float s = 0.f;
#pragma unroll
    for (int a = 0; a < 5; ++a)
      s += aw3[(size_t)(b * 64 + n) * 5 + a] * enc3[((size_t)a * 32 + b) * 128 + k];
    concat_bf[(size_t)row * CIN + 1536 + k] = (bf16)s;
  } else {
    int j = i - NB * 128;
    if (j < 16384) hid[j] = rnn[(size_t)63 * 16384 + j];
  }
}

// ---------------------------------------------------------------------------
// k_gate: gate[n,b,j] = tanh(gate_W[j,:] . [embedded, rnn, e4] + gate_b[j])
// ---------------------------------------------------------------------------
__global__ __launch_bounds__(256) void k_gate(const float* __restrict__ embedded,
                                              const float* __restrict__ rnn,
                                              const float* __restrict__ misc,
                                              const float* __restrict__ gW,
                                              const float* __restrict__ gb,
                                              float* __restrict__ gate) {
  int i = blockIdx.x * 256 + threadIdx.x;
  if (i >= NB * ANUMC) return;
  int row = i / ANUMC, j = i % ANUMC;
  int b = row & 31;
  const float* w = gW + (size_t)j * 1044;
  const float* e = embedded + (size_t)row * 512;
  const float* r = rnn + (size_t)row * 512;
  float s = gb[j];
#pragma unroll 4
  for (int k = 0; k < 512; k += 4) {
    float4 a = *(const float4*)(e + k);
    float4 ww = *(const float4*)(w + k);
    s += a.x * ww.x + a.y * ww.y + a.z * ww.z + a.w * ww.w;
  }
#pragma unroll 4
  for (int k = 0; k < 512; k += 4) {
    float4 a = *(const float4*)(r + k);
    float4 ww = *(const float4*)(w + 512 + k);
    s += a.x * ww.x + a.y * ww.y + a.z * ww.z + a.w * ww.w;
  }
  const float* e4 = misc + 1792 + b * ANUMC;
#pragma unroll
  for (int q = 0; q < ANUMC; ++q) s += w[1024 + q] * e4[q];
  gate[i] = tanhf(s);
}

// ---------------------------------------------------------------------------
// k_aspect: output[:, :, aspect_ids] += tile(gate,100)  (duplicates accumulate)
// one block per (n,b) row.
// ---------------------------------------------------------------------------
__global__ __launch_bounds__(256) void k_aspect(const int* __restrict__ ids,
                                                const float* __restrict__ gate,
                                                float* __restrict__ out) {
  __shared__ float gs[ANUMC];
  int row = blockIdx.x;
  if (threadIdx.x < ANUMC) gs[threadIdx.x] = gate[(size_t)row * ANUMC + threadIdx.x];
  __syncthreads();
  float* orow = out + (size_t)row * VOC;
  for (int k = threadIdx.x; k < 2000; k += 256) {
    atomicAdd(orow + ids[k], gs[k % ANUMC]);
  }
}

// ---------------------------------------------------------------------------
// launcher
// ---------------------------------------------------------------------------
extern "C" void kernel_launch(void* const* d_in, const int* in_sizes, int n_in,
                              void* d_out, int out_size, void* d_ws, size_t ws_size,
                              hipStream_t stream) {
  const int* seq = (const int*)d_in[0];
  const float* lasth = (const float*)d_in[1];
  const float* enc1 = (const float*)d_in[2];
  const float* enc2 = (const float*)d_in[3];
  const float* enc3 = (const float*)d_in[4];
  const float* enc4 = (const float*)d_in[5];
  const int* aspect = (const int*)d_in[6];
  const float* emb = (const float*)d_in[7];
  const float* Wih = (const float*)d_in[8];
  const float* Whh = (const float*)d_in[9];
  const float* bih = (const float*)d_in[10];
  const float* bhh = (const float*)d_in[11];
  const float* attn_W = (const float*)d_in[12];
  const float* attn_b = (const float*)d_in[13];
  const float* attn_v = (const float*)d_in[14];
  const float* attr_W = (const float*)d_in[15];
  const float* attr_b = (const float*)d_in[16];
  const float* attr_v = (const float*)d_in[17];
  const float* cW = (const float*)d_in[18];
  const float* cbias = (const float*)d_in[19];
  const float* oW = (const float*)d_in[20];
  const float* ob = (const float*)d_in[21];
  const float* gW = (const float*)d_in[22];
  const float* gb = (const float*)d_in[23];
  const float* pW = (const float*)d_in[24];
  const float* pb = (const float*)d_in[25];

  char* ws = (char*)d_ws;
  float* misc = (float*)(ws + 0);                    // 64 KB
  float* embedded = (float*)(ws + 65536);            // 4 MB
  float* gi = (float*)(ws + 4259840);                // 12 MB
  float* rnn = (float*)(ws + 16842752);              // 4 MB
  bf16* emb_bf = (bf16*)(ws + 21037056);             // 2 MB
  bf16* Wih_bf = (bf16*)(ws + 23134208);             // 1.5 MB
  bf16* cW_bf = (bf16*)(ws + 24707072);              // 1.6 MB
  bf16* oW_bf = (bf16*)(ws + 26411008);              // 32.8 MB
  bf16* concat_bf = (bf16*)(ws + 59179008);          // 6.8 MB
  bf16* cout_bf = (bf16*)(ws + 65994752);            // 2 MB
  bf16* Whh_pad = (bf16*)(ws + 68091904);            // 2 MB   (end ~70.2 MB)
  int* bar = (int*)(misc + 12032);

  float* out = (float*)d_out;
  float* hid_out = out + 65536000;
  float* aw1 = out + 65552384;
  float* aw2 = out + 66076672;
  float* aw3 = out + 66142208;
  float* gate = out + 66152448;

  k_zero<<<1, 256, 0, stream>>>(bar);
  k_vec<<<4, 256, 0, stream>>>(attn_W, attn_b, attn_v, attr_W, attr_b, attr_v, enc4, pW, pb, misc);
  k_embcvt<<<78592, 256, 0, stream>>>(seq, emb, embedded, emb_bf, Wih, Wih_bf, cW, cW_bf, oW,
                                      oW_bf, Whh, Whh_pad);
  k_c<<<37, 256, 0, stream>>>(enc1, enc2, enc3, misc);
  k_gemm_bt<0><<<dim3(12, 16), 256, 0, stream>>>(emb_bf, Wih_bf, bih, gi, nullptr, NB, G3H, 512);
  k_gru<<<128, 256, 0, stream>>>(gi, Whh_pad, bhh, lasth, rnn, concat_bf, bar);
  k_attnrow<<<512, 256, 0, stream>>>(rnn, misc, aw1, aw2, aw3);
  k_ctx<256, 512><<<128, 256, 0, stream>>>(aw1, enc1, concat_bf);
  k_ctx<32, 1024><<<128, 256, 0, stream>>>(aw2, enc2, concat_bf);
  k_ctx3_misc<<<1088, 256, 0, stream>>>(aw3, enc3, rnn, concat_bf, hid_out);
  k_gate<<<160, 256, 0, stream>>>(embedded, rnn, misc, gW, gb, gate);
  k_gemm_bt<1><<<dim3(4, 16), 256, 0, stream>>>(concat_bf, cW_bf, cbias, nullptr, cout_bf, NB,
                                                512, CIN);
  k_gemm_bt<0><<<dim3(250, 16), 256, 0, stream>>>(cout_bf, oW_bf, ob, out, nullptr, NB, VOC, 512);
  k_aspect<<<2048, 256, 0, stream>>>(aspect, gate, out);
}

// Round 2
// 1207.237 us; speedup vs baseline: 2.2070x; 2.2070x over previous
//
#include <hip/hip_runtime.h>
#include <hip/hip_bf16.h>

// ---------------------------------------------------------------------------
// Problem constants (from reference)
// ---------------------------------------------------------------------------
#define HDIM 512
#define KA   128
#define VOC  32000
#define ANUMC 20
#define NSEQ 64
#define BATCH 32
#define TLEN 256
#define SLEN 32
#define ALEN 5
#define NB   2048          // NSEQ*BATCH
#define CIN  1664          // 3H + KA
#define G3H  1536
#define GB   64            // GRU persistent blocks

typedef __bf16 bf16;
typedef bf16 v8bf __attribute__((ext_vector_type(8)));
typedef float v4f __attribute__((ext_vector_type(4)));

#define DEV __device__ __forceinline__

DEV float sigmoidf_(float x) { return 1.f / (1.f + expf(-x)); }

// ---------------------------------------------------------------------------
// k_zero: zero the barrier flags (ws is poisoned 0xAA before every launch)
// GB flags spaced 32 ints (128 B) apart -> 2048 ints.
// ---------------------------------------------------------------------------
__global__ void k_zero(int* bar) {
  for (int i = threadIdx.x; i < GB * 32; i += 256) bar[i] = 0;
}

// ---------------------------------------------------------------------------
// k_vec: small precomputations
//  u1a = attn_W[:, :H].T @ attn_v      (512)   @ misc+0
//  u1e = attn_W[:, H:].T @ attn_v      (512)   @ misc+512
//  u3h = attr_W[:, :H].T @ attr_v      (512)   @ misc+1024
//  u3e = attr_W[:, H:].T @ attr_v      (128)   @ misc+1536
//  bv1 = dot(attn_b, attn_v)                   @ misc+1664
//  bv3 = dot(attr_b, attr_v)                   @ misc+1665
//  e4[b,j] (proj of concat(enc4[0],enc4[1]))   @ misc+1792 (640)
// ---------------------------------------------------------------------------
__global__ void k_vec(const float* __restrict__ attn_W, const float* __restrict__ attn_b,
                      const float* __restrict__ attn_v,
                      const float* __restrict__ attr_W, const float* __restrict__ attr_b,
                      const float* __restrict__ attr_v,
                      const float* __restrict__ enc4, const float* __restrict__ pW,
                      const float* __restrict__ pb, float* __restrict__ misc) {
  int tid = threadIdx.x;
  int blk = blockIdx.x;
  if (blk == 0) {
    for (int i = tid; i < 512; i += 256) {
      float s = 0.f;
      for (int j = 0; j < 512; ++j) s += attn_W[j * 1024 + i] * attn_v[j];
      misc[i] = s;
    }
  } else if (blk == 1) {
    for (int i = tid; i < 512; i += 256) {
      float s = 0.f;
      for (int j = 0; j < 512; ++j) s += attn_W[j * 1024 + 512 + i] * attn_v[j];
      misc[512 + i] = s;
    }
  } else if (blk == 2) {
    for (int i = tid; i < 512; i += 256) {
      float s = 0.f;
      for (int j = 0; j < 512; ++j) s += attr_W[j * 640 + i] * attr_v[j];
      misc[1024 + i] = s;
    }
  } else {
    for (int i = tid; i < 128; i += 256) {
      float s = 0.f;
      for (int j = 0; j < 512; ++j) s += attr_W[j * 640 + 512 + i] * attr_v[j];
      misc[1536 + i] = s;
    }
    if (tid == 128) {
      float s = 0.f;
      for (int j = 0; j < 512; ++j) s += attn_b[j] * attn_v[j];
      misc[1664] = s;
    }
    if (tid == 129) {
      float s = 0.f;
      for (int j = 0; j < 512; ++j) s += attr_b[j] * attr_v[j];
      misc[1665] = s;
    }
    for (int i = tid; i < BATCH * ANUMC; i += 256) {
      int b = i / ANUMC, j = i % ANUMC;
      float s = pb[j];
      for (int q = 0; q < ANUMC; ++q) s += pW[j * 40 + q] * enc4[b * ANUMC + q];
      for (int q = 0; q < ANUMC; ++q) s += pW[j * 40 + 20 + q] * enc4[BATCH * ANUMC + b * ANUMC + q];
      misc[1792 + i] = s;
    }
  }
}

// ---------------------------------------------------------------------------
// k_embcvt: embedding gather (fp32 + bf16) and weight fp32->bf16 conversions
// segments: [0, 1048576)        embedded / emb_bf
//           [.., +786432)       Wih_bf
//           [.., +851968)       cW_bf
//           [.., +16384000)     oW_bf
// total 19,070,976 -> grid 74496 x 256
// ---------------------------------------------------------------------------
__global__ void k_embcvt(const int* __restrict__ seq, const float* __restrict__ emb,
                         float* __restrict__ embedded, bf16* __restrict__ emb_bf,
                         const float* __restrict__ Wih, bf16* __restrict__ Wih_bf,
                         const float* __restrict__ cW, bf16* __restrict__ cW_bf,
                         const float* __restrict__ oW, bf16* __restrict__ oW_bf) {
  size_t i = (size_t)blockIdx.x * 256 + threadIdx.x;
  const size_t s0 = 1048576, s1 = s0 + 786432, s2 = s1 + 851968, s3 = s2 + 16384000;
  if (i < s0) {
    int row = (int)(i >> 9), col = (int)(i & 511);
    float v = emb[(size_t)seq[row] * 512 + col];
    embedded[i] = v;
    emb_bf[i] = (bf16)v;
  } else if (i < s1) {
    size_t j = i - s0;
    Wih_bf[j] = (bf16)Wih[j];
  } else if (i < s2) {
    size_t j = i - s1;
    cW_bf[j] = (bf16)cW[j];
  } else if (i < s3) {
    size_t j = i - s2;
    oW_bf[j] = (bf16)oW[j];
  }
}

// ---------------------------------------------------------------------------
// k_c: c1[t*32+b] = enc1[t,b,:] . u1e ; c2 (enc2, u1e) ; c3 (enc3, u3e)
// ---------------------------------------------------------------------------
__global__ void k_c(const float* __restrict__ enc1, const float* __restrict__ enc2,
                    const float* __restrict__ enc3, float* __restrict__ misc) {
  int i = blockIdx.x * 256 + threadIdx.x;
  const float* u1e = misc + 512;
  const float* u3e = misc + 1536;
  if (i < 8192) {
    const float* row = enc1 + (size_t)i * 512;
    float s = 0.f;
#pragma unroll 4
    for (int j = 0; j < 512; j += 4) {
      float4 a = *(const float4*)(row + j);
      float4 u = *(const float4*)(u1e + j);
      s += a.x * u.x + a.y * u.y + a.z * u.z + a.w * u.w;
    }
    misc[2560 + i] = s;
  } else if (i < 8192 + 1024) {
    int k = i - 8192;
    const float* row = enc2 + (size_t)k * 512;
    float s = 0.f;
#pragma unroll 4
    for (int j = 0; j < 512; j += 4) {
      float4 a = *(const float4*)(row + j);
      float4 u = *(const float4*)(u1e + j);
      s += a.x * u.x + a.y * u.y + a.z * u.z + a.w * u.w;
    }
    misc[10752 + k] = s;
  } else if (i < 8192 + 1024 + 160) {
    int k = i - 9216;
    const float* row = enc3 + (size_t)k * 128;
    float s = 0.f;
#pragma unroll 4
    for (int j = 0; j < 128; j += 4) {
      float4 a = *(const float4*)(row + j);
      float4 u = *(const float4*)(u3e + j);
      s += a.x * u.x + a.y * u.y + a.z * u.z + a.w * u.w;
    }
    misc[11776 + k] = s;
  }
}

// ---------------------------------------------------------------------------
// Generic NT GEMM: C[m,n] = sum_k A[m,k]*B[n,k] (+bias[n])
// 128x128 tile, BK=64, 4 waves, mfma_f32_16x16x32_bf16, XOR-swizzled LDS.
// EPI 0: Cf = acc+bias (fp32) ; EPI 1: Cb = bf16(tanh(acc+bias))
// Requires M%128==0, N%128==0, K%64==0.
// ---------------------------------------------------------------------------
template <int EPI>
__global__ __launch_bounds__(256) void k_gemm_bt(const bf16* __restrict__ A,
                                                 const bf16* __restrict__ Bm,
                                                 const float* __restrict__ bias,
                                                 float* __restrict__ Cf, bf16* __restrict__ Cb,
                                                 int M, int Nn, int Kd) {
  __shared__ __align__(16) unsigned short As[128 * 64];
  __shared__ __align__(16) unsigned short Bs[128 * 64];
  int tid = threadIdx.x;
  int m0 = blockIdx.y * 128;
  int n0 = blockIdx.x * 128;
  int lane = tid & 63;
  int wv = tid >> 6;
  int wm = wv & 1, wn = wv >> 1;
  int l15 = lane & 15, quad = lane >> 4;
  int srow = tid >> 3;  // 0..31
  int sch = tid & 7;    // 0..7

  v4f acc[4][4];
#pragma unroll
  for (int i = 0; i < 4; ++i)
#pragma unroll
    for (int j = 0; j < 4; ++j) acc[i][j] = (v4f){0.f, 0.f, 0.f, 0.f};

  for (int kb = 0; kb < Kd; kb += 64) {
#pragma unroll
    for (int r = 0; r < 4; ++r) {
      int row = r * 32 + srow;
      uint4 va = *(const uint4*)(A + (size_t)(m0 + row) * Kd + kb + sch * 8);
      *(uint4*)((char*)As + row * 128 + ((sch ^ (row & 7)) << 4)) = va;
      uint4 vb = *(const uint4*)(Bm + (size_t)(n0 + row) * Kd + kb + sch * 8);
      *(uint4*)((char*)Bs + row * 128 + ((sch ^ (row & 7)) << 4)) = vb;
    }
    __syncthreads();
#pragma unroll
    for (int ks = 0; ks < 2; ++ks) {
      v8bf af[4], bfr[4];
      int c = ks * 4 + quad;
#pragma unroll
      for (int i = 0; i < 4; ++i) {
        int mr = wm * 64 + i * 16 + l15;
        af[i] = *(const v8bf*)((const char*)As + mr * 128 + ((c ^ (mr & 7)) << 4));
      }
#pragma unroll
      for (int j = 0; j < 4; ++j) {
        int nr = wn * 64 + j * 16 + l15;
        bfr[j] = *(const v8bf*)((const char*)Bs + nr * 128 + ((c ^ (nr & 7)) << 4));
      }
#pragma unroll
      for (int i = 0; i < 4; ++i)
#pragma unroll
        for (int j = 0; j < 4; ++j)
          acc[i][j] = __builtin_amdgcn_mfma_f32_16x16x32_bf16(af[i], bfr[j], acc[i][j], 0, 0, 0);
    }
    __syncthreads();
  }
  // epilogue: C/D layout col = lane&15, row = quad*4 + reg  [m89/m91]
#pragma unroll
  for (int i = 0; i < 4; ++i) {
    int gr0 = m0 + wm * 64 + i * 16 + quad * 4;
#pragma unroll
    for (int j = 0; j < 4; ++j) {
      int gc = n0 + wn * 64 + j * 16 + l15;
      float bs = bias[gc];
#pragma unroll
      for (int reg = 0; reg < 4; ++reg) {
        float v = acc[i][j][reg] + bs;
        if (EPI == 1)
          Cb[(size_t)(gr0 + reg) * Nn + gc] = (bf16)tanhf(v);
        else
          Cf[(size_t)(gr0 + reg) * Nn + gc] = v;
      }
    }
  }
}

// ---------------------------------------------------------------------------
// k_gru: persistent recurrence, GB=64 blocks x 256 threads; block owns 8 cols.
// NO device fences (round-1 post-mortem: __threadfence = per-XCD L2
// wb+inv = 27 us/step). Cross-block h exchange goes through an LLC-coherent
// buffer h_x via RELAXED/AGENT atomics (sc0 sc1 path, completes at Infinity
// Cache). Barrier: per-block arrive word on its own 128B line; wave 0 polls
// all 64 flags with one 64-lane gather + __all. __syncthreads drains vmcnt
// per wave (m97 asm evidence), so data is at LLC before the flag store issues.
// ---------------------------------------------------------------------------
__global__ __launch_bounds__(256) void k_gru(const float* __restrict__ gi,
                                             const float* __restrict__ Whh,
                                             const float* __restrict__ bhh,
                                             const float* __restrict__ lasth,
                                             float* __restrict__ rnn,
                                             bf16* __restrict__ concat_bf,
                                             bf16* __restrict__ h_x,
                                             int* __restrict__ bar) {
  // whh: 24 real rows; B-frag reads for the second n-tile touch phantom rows
  // 24..31 which land in hs (garbage) -> those MFMA output columns are never
  // stored (guarded). Keep hs directly after whh.
  struct SMEM {
    unsigned short whh[24 * 512];  // 24 KB
    unsigned short hs[32 * 512];   // 32 KB
    float gh[32 * 29];             // 3.7 KB (stride 29: conflict-free acc writes)
    unsigned short hnew[256];
  };
  __shared__ __align__(16) SMEM sm;
  int tid = threadIdx.x;
  int blk = blockIdx.x;
  int c0 = blk * 8;

  // one-time: 24 Whh rows (3 gates x 8 cols) -> bf16 LDS, XOR-swizzled
  for (int idx = tid; idx < 24 * 64; idx += 256) {
    int row = idx >> 6, cc = idx & 63;
    int g = row >> 3, jj = row & 7;
    const float* src = Whh + (size_t)(g * 512 + c0 + jj) * 512 + cc * 8;
    float4 x = *(const float4*)src;
    float4 y = *(const float4*)(src + 4);
    v8bf vv;
    vv[0] = (bf16)x.x; vv[1] = (bf16)x.y; vv[2] = (bf16)x.z; vv[3] = (bf16)x.w;
    vv[4] = (bf16)y.x; vv[5] = (bf16)y.y; vv[6] = (bf16)y.z; vv[7] = (bf16)y.w;
    *(v8bf*)((char*)sm.whh + row * 1024 + ((cc ^ (row & 7)) << 4)) = vv;
  }

  int lane = tid & 63;
  int w = tid >> 6;
  int l15 = lane & 15, quad = lane >> 4;
  int m0 = (w & 1) * 16;   // batch tile
  int n0 = (w >> 1) * 16;  // gate-row tile (rows >=24 phantom)

  int cb = tid >> 3, j = tid & 7, c = c0 + j;
  float hprev = lasth[cb * 512 + c];
  float b_r = bhh[c], b_z = bhh[512 + c], b_n = bhh[1024 + c];

  for (int t = 0; t < 64; ++t) {
    // prefetch this step's gi (independent of h; hides under stage+MFMA)
    const float* gii = gi + ((size_t)t * 32 + cb) * G3H;
    float g_r = gii[c];
    float g_z = gii[512 + c];
    float g_n = gii[1024 + c];

    // ---- stage h (bf16) into LDS ----
    if (t == 0) {
#pragma unroll
      for (int rnd = 0; rnd < 8; ++rnd) {
        int ch = rnd * 256 + tid;
        int bb = ch >> 6, cc = ch & 63;
        const float* hp = lasth + bb * 512 + cc * 8;
        float4 x = *(const float4*)hp;
        float4 y = *(const float4*)(hp + 4);
        v8bf vv;
        vv[0] = (bf16)x.x; vv[1] = (bf16)x.y; vv[2] = (bf16)x.z; vv[3] = (bf16)x.w;
        vv[4] = (bf16)y.x; vv[5] = (bf16)y.y; vv[6] = (bf16)y.z; vv[7] = (bf16)y.w;
        *(v8bf*)((char*)sm.hs + bb * 1024 + ((cc ^ (bb & 7)) << 4)) = vv;
      }
    } else {
#pragma unroll
      for (int rnd = 0; rnd < 8; ++rnd) {
        int ch = rnd * 256 + tid;
        int bb = ch >> 6, cc = ch & 63;
        const unsigned long long* src = (const unsigned long long*)(h_x + bb * 512 + cc * 8);
        unsigned long long a0 = __hip_atomic_load(src, __ATOMIC_RELAXED, __HIP_MEMORY_SCOPE_AGENT);
        unsigned long long a1 = __hip_atomic_load(src + 1, __ATOMIC_RELAXED, __HIP_MEMORY_SCOPE_AGENT);
        uint4 v;
        v.x = (unsigned)a0; v.y = (unsigned)(a0 >> 32);
        v.z = (unsigned)a1; v.w = (unsigned)(a1 >> 32);
        *(uint4*)((char*)sm.hs + bb * 1024 + ((cc ^ (bb & 7)) << 4)) = v;
      }
    }
    __syncthreads();

    // ---- MFMA: gh[batch 32][gaterow 24] (one 16x16 tile pair per wave) ----
    {
      v4f acc = (v4f){0.f, 0.f, 0.f, 0.f};
#pragma unroll
      for (int it = 0; it < 16; ++it) {
        int cc = it * 4 + quad;
        int mr = m0 + l15;
        v8bf af = *(const v8bf*)((const char*)sm.hs + mr * 1024 + ((cc ^ (mr & 7)) << 4));
        int nr = n0 + l15;
        v8bf bfr = *(const v8bf*)((const char*)sm.whh + nr * 1024 + ((cc ^ (nr & 7)) << 4));
        acc = __builtin_amdgcn_mfma_f32_16x16x32_bf16(af, bfr, acc, 0, 0, 0);
      }
      if (n0 == 0 || l15 < 8) {
#pragma unroll
        for (int reg = 0; reg < 4; ++reg)
          sm.gh[(m0 + quad * 4 + reg) * 29 + n0 + l15] = acc[reg];
      }
    }
    __syncthreads();

    // ---- combine gates; thread owns (batch cb, col c) ----
    {
      float ar = sm.gh[cb * 29 + j] + b_r;
      float az = sm.gh[cb * 29 + 8 + j] + b_z;
      float an = sm.gh[cb * 29 + 16 + j] + b_n;
      float rg = sigmoidf_(g_r + ar);
      float zg = sigmoidf_(g_z + az);
      float ng = tanhf(g_n + rg * an);
      float hn = (1.f - zg) * ng + zg * hprev;
      hprev = hn;
      rnn[((size_t)t * 32 + cb) * 512 + c] = hn;
      bf16 hb = (bf16)hn;
      concat_bf[((size_t)t * 32 + cb) * CIN + c] = hb;
      sm.hnew[tid] = *(unsigned short*)&hb;
    }

    if (t < 63) {
      __syncthreads();  // hnew visible in LDS
      // publish h to LLC: 64 threads pack 4 bf16 -> u64 relaxed agent store
      if (tid < 64) {
        int q = tid;
        int cbq = q >> 1, j0 = (q & 1) * 4;
        const unsigned short* hp = sm.hnew + q * 4;
        unsigned long long pk = (unsigned long long)hp[0] | ((unsigned long long)hp[1] << 16) |
                                ((unsigned long long)hp[2] << 32) |
                                ((unsigned long long)hp[3] << 48);
        __hip_atomic_store((unsigned long long*)(h_x + cbq * 512 + c0 + j0), pk,
                           __ATOMIC_RELAXED, __HIP_MEMORY_SCOPE_AGENT);
      }
      __syncthreads();  // per-wave vmcnt(0) drain: h_x stores are at LLC now
      if (tid == 0)
        __hip_atomic_store(&bar[blk * 32], t + 1, __ATOMIC_RELAXED, __HIP_MEMORY_SCOPE_AGENT);
      if (w == 0) {
        int target = t + 1;
        for (;;) {
          int v = __hip_atomic_load(&bar[lane * 32], __ATOMIC_RELAXED, __HIP_MEMORY_SCOPE_AGENT);
          if (__all(v >= target)) break;
          __builtin_amdgcn_s_sleep(1);
        }
      }
      __atomic_signal_fence(__ATOMIC_SEQ_CST);
      __syncthreads();
    }
  }
}

// ---------------------------------------------------------------------------
// k_attnrow: per (n,b) row: a1,a3 dots + all three softmaxes -> aw1,aw2,aw3
// one wave per row; 4 waves per block; grid 512.
// ---------------------------------------------------------------------------
__global__ __launch_bounds__(256) void k_attnrow(const float* __restrict__ rnn,
                                                 const float* __restrict__ misc,
                                                 float* __restrict__ aw1,
                                                 float* __restrict__ aw2,
                                                 float* __restrict__ aw3) {
  int wv = (blockIdx.x * 256 + threadIdx.x) >> 6;
  int lane = threadIdx.x & 63;
  if (wv >= 2048) return;
  int n = wv >> 5, b = wv & 31;
  const float* u1a = misc;
  const float* u3h = misc + 1024;
  const float* c1 = misc + 2560;
  const float* c2 = misc + 10752;
  const float* c3 = misc + 11776;
  const float* row = rnn + (size_t)(n * 32 + b) * 512;
  float s1 = 0.f, s3 = 0.f;
#pragma unroll
  for (int q = 0; q < 8; ++q) {
    int j = lane * 8 + q;
    float rv = row[j];
    s1 += rv * u1a[j];
    s3 += rv * u3h[j];
  }
  for (int o = 32; o > 0; o >>= 1) {
    s1 += __shfl_down(s1, o);
    s3 += __shfl_down(s3, o);
  }
  s1 = __shfl(s1, 0) + misc[1664];
  s3 = __shfl(s3, 0) + misc[1665];

  // aw1 over T=256
  float e[4];
  float mx = -1e30f;
#pragma unroll
  for (int q = 0; q < 4; ++q) {
    int t = q * 64 + lane;
    e[q] = tanhf(s1 + c1[t * 32 + b]);
    mx = fmaxf(mx, e[q]);
  }
  for (int o = 32; o > 0; o >>= 1) mx = fmaxf(mx, __shfl_xor(mx, o));
  float sum = 0.f;
#pragma unroll
  for (int q = 0; q < 4; ++q) {
    e[q] = expf(e[q] - mx);
    sum += e[q];
  }
  for (int o = 32; o > 0; o >>= 1) sum += __shfl_xor(sum, o);
  float inv = 1.f / sum;
  size_t base1 = (size_t)(b * 64 + n) * 256;
#pragma unroll
  for (int q = 0; q < 4; ++q) aw1[base1 + q * 64 + lane] = e[q] * inv;

  // aw2 over S=32
  float e2 = (lane < 32) ? tanhf(s1 + c2[lane * 32 + b]) : -1e30f;
  float m2 = e2;
  for (int o = 32; o > 0; o >>= 1) m2 = fmaxf(m2, __shfl_xor(m2, o));
  float x2 = (lane < 32) ? expf(e2 - m2) : 0.f;
  float sm2 = x2;
  for (int o = 32; o > 0; o >>= 1) sm2 += __shfl_xor(sm2, o);
  if (lane < 32) aw2[(size_t)(b * 64 + n) * 32 + lane] = x2 / sm2;

  // aw3 over A=5
  float e3 = (lane < 5) ? tanhf(s3 + c3[lane * 32 + b]) : -1e30f;
  float m3 = e3;
  for (int o = 32; o > 0; o >>= 1) m3 = fmaxf(m3, __shfl_xor(m3, o));
  float x3 = (lane < 5) ? expf(e3 - m3) : 0.f;
  float sm3 = x3;
  for (int o = 32; o > 0; o >>= 1) sm3 += __shfl_xor(sm3, o);
  if (lane < 5) aw3[(size_t)(b * 64 + n) * 5 + lane] = x3 / sm3;
}

// ---------------------------------------------------------------------------
// k_ctx: ctx[n,b,col] = sum_te aw[b,n,te]*enc[te,b,col] -> bf16 into concat.
// grid 128: b(32) x q(2: 256-col half) x nh(2: 32-n half).
// ---------------------------------------------------------------------------
template <int TL, int COFF>
__global__ __launch_bounds__(256) void k_ctx(const float* __restrict__ aw,
                                             const float* __restrict__ enc,
                                             bf16* __restrict__ concat_bf) {
  __shared__ __align__(16) float awsT[TL * 36];
  int tid = threadIdx.x;
  int bx = blockIdx.x;
  int b = bx >> 2, q = (bx >> 1) & 1, nh = bx & 1;
  for (int i = tid; i < 32 * TL; i += 256) {
    int n = i / TL, te = i % TL;
    awsT[te * 36 + n] = aw[(size_t)b * 64 * TL + (size_t)(nh * 32 + n) * TL + te];
  }
  __syncthreads();
  int col = q * 256 + tid;
  float4 acc[8];
#pragma unroll
  for (int n4 = 0; n4 < 8; ++n4) acc[n4] = make_float4(0.f, 0.f, 0.f, 0.f);
  for (int te = 0; te < TL; ++te) {
    float v = enc[((size_t)te * 32 + b) * 512 + col];
#pragma unroll
    for (int n4 = 0; n4 < 8; ++n4) {
      float4 wv = *(const float4*)(awsT + te * 36 + n4 * 4);
      acc[n4].x += wv.x * v;
      acc[n4].y += wv.y * v;
      acc[n4].z += wv.z * v;
      acc[n4].w += wv.w * v;
    }
  }
#pragma unroll
  for (int n4 = 0; n4 < 8; ++n4) {
    int ng = nh * 32 + n4 * 4;
    concat_bf[((size_t)(ng + 0) * 32 + b) * CIN + COFF + col] = (bf16)acc[n4].x;
    concat_bf[((size_t)(ng + 1) * 32 + b) * CIN + COFF + col] = (bf16)acc[n4].y;
    concat_bf[((size_t)(ng + 2) * 32 + b) * CIN + COFF + col] = (bf16)acc[n4].z;
    concat_bf[((size_t)(ng + 3) * 32 + b) * CIN + COFF + col] = (bf16)acc[n4].w;
  }
}

// ---------------------------------------------------------------------------
// k_ctx3_misc: ctx3 (5-term) into concat cols [1536,1664) + hidden copy
// ---------------------------------------------------------------------------
__global__ void k_ctx3_misc(const float* __restrict__ aw3, const float* __restrict__ enc3,
                            const float* __restrict__ rnn, bf16* __restrict__ concat_bf,
                            float* __restrict__ hid) {
  int i = blockIdx.x * 256 + threadIdx.x;
  if (i < NB * 128) {
    int row = i >> 7, k = i & 127;
    int n = row >> 5, b = row & 31;
    float s = 0.f;
#pragma unroll
    for (int a = 0; a < 5; ++a)
      s += aw3[(size_t)(b * 64 + n) * 5 + a] * enc3[((size_t)a * 32 + b) * 128 + k];
    concat_bf[(size_t)row * CIN + 1536 + k] = (bf16)s;
  } else {
    int j = i - NB * 128;
    if (j < 16384) hid[j] = rnn[(size_t)63 * 16384 + j];
  }
}

// ---------------------------------------------------------------------------
// k_gate: gate[n,b,j] = tanh(gate_W[j,:] . [embedded, rnn, e4] + gate_b[j])
// ---------------------------------------------------------------------------
__global__ __launch_bounds__(256) void k_gate(const float* __restrict__ embedded,
                                              const float* __restrict__ rnn,
                                              const float* __restrict__ misc,
                                              const float* __restrict__ gW,
                                              const float* __restrict__ gb,
                                              float* __restrict__ gate) {
  int i = blockIdx.x * 256 + threadIdx.x;
  if (i >= NB * ANUMC) return;
  int row = i / ANUMC, j = i % ANUMC;
  int b = row & 31;
  const float* w = gW + (size_t)j * 1044;
  const float* e = embedded + (size_t)row * 512;
  const float* r = rnn + (size_t)row * 512;
  float s = gb[j];
#pragma unroll 4
  for (int k = 0; k < 512; k += 4) {
    float4 a = *(const float4*)(e + k);
    float4 ww = *(const float4*)(w + k);
    s += a.x * ww.x + a.y * ww.y + a.z * ww.z + a.w * ww.w;
  }
#pragma unroll 4
  for (int k = 0; k < 512; k += 4) {
    float4 a = *(const float4*)(r + k);
    float4 ww = *(const float4*)(w + 512 + k);
    s += a.x * ww.x + a.y * ww.y + a.z * ww.z + a.w * ww.w;
  }
  const float* e4 = misc + 1792 + b * ANUMC;
#pragma unroll
  for (int q = 0; q < ANUMC; ++q) s += w[1024 + q] * e4[q];
  gate[i] = tanhf(s);
}

// ---------------------------------------------------------------------------
// k_aspect: output[:, :, aspect_ids] += tile(gate,100)  (duplicates accumulate)
// ---------------------------------------------------------------------------
__global__ __launch_bounds__(256) void k_aspect(const int* __restrict__ ids,
                                                const float* __restrict__ gate,
                                                float* __restrict__ out) {
  __shared__ float gs[ANUMC];
  int row = blockIdx.x;
  if (threadIdx.x < ANUMC) gs[threadIdx.x] = gate[(size_t)row * ANUMC + threadIdx.x];
  __syncthreads();
  float* orow = out + (size_t)row * VOC;
  for (int k = threadIdx.x; k < 2000; k += 256) {
    atomicAdd(orow + ids[k], gs[k % ANUMC]);
  }
}

// ---------------------------------------------------------------------------
// launcher
// ---------------------------------------------------------------------------
extern "C" void kernel_launch(void* const* d_in, const int* in_sizes, int n_in,
                              void* d_out, int out_size, void* d_ws, size_t ws_size,
                              hipStream_t stream) {
  const int* seq = (const int*)d_in[0];
  const float* lasth = (const float*)d_in[1];
  const float* enc1 = (const float*)d_in[2];
  const float* enc2 = (const float*)d_in[3];
  const float* enc3 = (const float*)d_in[4];
  const float* enc4 = (const float*)d_in[5];
  const int* aspect = (const int*)d_in[6];
  const float* emb = (const float*)d_in[7];
  const float* Wih = (const float*)d_in[8];
  const float* Whh = (const float*)d_in[9];
  const float* bih = (const float*)d_in[10];
  const float* bhh = (const float*)d_in[11];
  const float* attn_W = (const float*)d_in[12];
  const float* attn_b = (const float*)d_in[13];
  const float* attn_v = (const float*)d_in[14];
  const float* attr_W = (const float*)d_in[15];
  const float* attr_b = (const float*)d_in[16];
  const float* attr_v = (const float*)d_in[17];
  const float* cW = (const float*)d_in[18];
  const float* cbias = (const float*)d_in[19];
  const float* oW = (const float*)d_in[20];
  const float* ob = (const float*)d_in[21];
  const float* gW = (const float*)d_in[22];
  const float* gb = (const float*)d_in[23];
  const float* pW = (const float*)d_in[24];
  const float* pb = (const float*)d_in[25];

  char* ws = (char*)d_ws;
  float* misc = (float*)(ws + 0);                    // 64 KB
  float* embedded = (float*)(ws + 65536);            // 4 MB
  float* gi = (float*)(ws + 4259840);                // 12 MB
  float* rnn = (float*)(ws + 16842752);              // 4 MB
  bf16* emb_bf = (bf16*)(ws + 21037056);             // 2 MB
  bf16* Wih_bf = (bf16*)(ws + 23134208);             // 1.5 MB
  bf16* cW_bf = (bf16*)(ws + 24707072);              // 1.6 MB
  bf16* oW_bf = (bf16*)(ws + 26411008);              // 32.8 MB
  bf16* concat_bf = (bf16*)(ws + 59179008);          // 6.8 MB
  bf16* cout_bf = (bf16*)(ws + 65994752);            // 2 MB
  bf16* h_x = (bf16*)(ws + 68091904);                // 32 KB LLC exchange buffer
  int* bar = (int*)(misc + 12032);                   // 64 flags x 128B

  float* out = (float*)d_out;
  float* hid_out = out + 65536000;
  float* aw1 = out + 65552384;
  float* aw2 = out + 66076672;
  float* aw3 = out + 66142208;
  float* gate = out + 66152448;

  k_zero<<<1, 256, 0, stream>>>(bar);
  k_vec<<<4, 256, 0, stream>>>(attn_W, attn_b, attn_v, attr_W, attr_b, attr_v, enc4, pW, pb, misc);
  k_embcvt<<<74496, 256, 0, stream>>>(seq, emb, embedded, emb_bf, Wih, Wih_bf, cW, cW_bf, oW,
                                      oW_bf);
  k_c<<<37, 256, 0, stream>>>(enc1, enc2, enc3, misc);
  k_gemm_bt<0><<<dim3(12, 16), 256, 0, stream>>>(emb_bf, Wih_bf, bih, gi, nullptr, NB, G3H, 512);
  k_gru<<<GB, 256, 0, stream>>>(gi, Whh, bhh, lasth, rnn, concat_bf, h_x, bar);
  k_attnrow<<<512, 256, 0, stream>>>(rnn, misc, aw1, aw2, aw3);
  k_ctx<256, 512><<<128, 256, 0, stream>>>(aw1, enc1, concat_bf);
  k_ctx<32, 1024><<<128, 256, 0, stream>>>(aw2, enc2, concat_bf);
  k_ctx3_misc<<<1088, 256, 0, stream>>>(aw3, enc3, rnn, concat_bf, hid_out);
  k_gate<<<160, 256, 0, stream>>>(embedded, rnn, misc, gW, gb, gate);
  k_gemm_bt<1><<<dim3(4, 16), 256, 0, stream>>>(concat_bf, cW_bf, cbias, nullptr, cout_bf, NB,
                                                512, CIN);
  k_gemm_bt<0><<<dim3(250, 16), 256, 0, stream>>>(cout_bf, oW_bf, ob, out, nullptr, NB, VOC, 512);
  k_aspect<<<2048, 256, 0, stream>>>(aspect, gate, out);
}